// Round 8
// baseline (1391.079 us; speedup 1.0000x reference)
//
#include <hip/hip_runtime.h>
#include <cstdint>
#include <cmath>

#define HID 96
#define INC 128
#define OUTC 40

// ---------------- threefry2x32 (JAX exact) ----------------
__device__ __forceinline__ unsigned rotl32d(unsigned x, int r){ return (x<<r)|(x>>(32-r)); }

__device__ __forceinline__ void tf2x32_dev(unsigned k0, unsigned k1, unsigned x0, unsigned x1,
                                           unsigned &y0, unsigned &y1){
  unsigned ks2 = k0 ^ k1 ^ 0x1BD11BDAu;
  x0 += k0; x1 += k1;
#define TFR(r) { x0 += x1; x1 = rotl32d(x1, r); x1 ^= x0; }
  TFR(13) TFR(15) TFR(26) TFR(6)   x0 += k1;  x1 += ks2 + 1u;
  TFR(17) TFR(29) TFR(16) TFR(24)  x0 += ks2; x1 += k0 + 2u;
  TFR(13) TFR(15) TFR(26) TFR(6)   x0 += k0;  x1 += k1 + 3u;
  TFR(17) TFR(29) TFR(16) TFR(24)  x0 += k1;  x1 += ks2 + 4u;
  TFR(13) TFR(15) TFR(26) TFR(6)   x0 += ks2; x1 += k0 + 5u;
#undef TFR
  y0 = x0; y1 = x1;
}

// Partitionable-mode 32-bit random bits for flat index idx (hi word of 64-bit iota == 0)
__device__ __forceinline__ unsigned tf_bits(unsigned k0, unsigned k1, unsigned idx){
  unsigned y0, y1; tf2x32_dev(k0, k1, 0u, idx, y0, y1); return y0 ^ y1;
}

__device__ __forceinline__ float u01_from_bits(unsigned bits){
  return __uint_as_float((bits >> 9) | 0x3f800000u) - 1.0f;
}

// XLA f32 ErfInv polynomial
__device__ __forceinline__ float erfinv_xla(float x){
  float w = -log1pf(-x*x);
  float p;
  if (w < 5.0f){
    w = w - 2.5f;
    p = 2.81022636e-08f;
    p = fmaf(p,w, 3.43273939e-07f);
    p = fmaf(p,w,-3.5233877e-06f);
    p = fmaf(p,w,-4.39150654e-06f);
    p = fmaf(p,w, 0.00021858087f);
    p = fmaf(p,w,-0.00125372503f);
    p = fmaf(p,w,-0.00417768164f);
    p = fmaf(p,w, 0.246640727f);
    p = fmaf(p,w, 1.50140941f);
  } else {
    w = sqrtf(w) - 3.0f;
    p = -0.000200214257f;
    p = fmaf(p,w, 0.000100950558f);
    p = fmaf(p,w, 0.00134934322f);
    p = fmaf(p,w,-0.00367342844f);
    p = fmaf(p,w, 0.00573950773f);
    p = fmaf(p,w,-0.0076224613f);
    p = fmaf(p,w, 0.00943887047f);
    p = fmaf(p,w, 1.00167406f);
    p = fmaf(p,w, 2.83297682f);
  }
  return p*x;
}

// ---------------- setup kernels ----------------
__global__ void k_detect(const unsigned* __restrict__ raw, int* flag){
  unsigned v = raw[2*threadIdx.x + 1];
  unsigned long long m = __ballot(v == 0u);
  if (threadIdx.x == 0) *flag = (m == 0xFFFFFFFFFFFFFFFFull) ? 1 : 0;
}

__global__ void k_convcount(const unsigned* __restrict__ raw, const int* __restrict__ flag,
                            int E, int* __restrict__ src, int* __restrict__ dst,
                            int* __restrict__ cnt){
  int e = blockIdx.x*256 + threadIdx.x; if (e >= E) return;
  int s, d;
  if (*flag){ s = (int)raw[2*(size_t)e]; d = (int)raw[2*((size_t)E + e)]; }
  else      { const int* r = (const int*)raw; s = r[e]; d = r[E + e]; }
  src[e] = s; dst[e] = d;
  atomicAdd(&cnt[d], 1);
}

__global__ void k_psum_histo(const int* __restrict__ cnt, int N,
                             int* __restrict__ psum, int* __restrict__ bcnt){
  __shared__ int sh[256];
  __shared__ int lh[64];
  int tid = threadIdx.x; int n = blockIdx.x*256 + tid;
  int v = (n < N) ? cnt[n] : 0;
  sh[tid] = v;
  if (tid < 64) lh[tid] = 0;
  __syncthreads();
  if (n < N) atomicAdd(&lh[min(v, 63)], 1);
  for (int off = 128; off > 0; off >>= 1){
    __syncthreads();
    if (tid < off) sh[tid] += sh[tid + off];
  }
  __syncthreads();
  if (tid == 0) psum[blockIdx.x] = sh[0];
  if (tid < 64){
    int c = lh[tid];
    if (c > 0) atomicAdd(&bcnt[tid], c);
  }
}

__global__ void k_scan2(int* __restrict__ psum, int nb, int* __restrict__ bcnt){
  __shared__ int sh[256];
  __shared__ int sb[64];
  int tid = threadIdx.x;
  int v = (tid < nb) ? psum[tid] : 0;
  sh[tid] = v;
  if (tid < 64) sb[tid] = bcnt[tid];
  __syncthreads();
  for (int off = 1; off < 256; off <<= 1){
    int t = (tid >= off) ? sh[tid - off] : 0;
    __syncthreads();
    sh[tid] += t;
    __syncthreads();
  }
  if (tid < nb) psum[tid] = sh[tid] - v;   // exclusive
  if (tid < 64){                           // descending: high degree first
    int off = 0;
    for (int b2 = tid+1; b2 < 64; b2++) off += sb[b2];
    bcnt[tid] = off;
  }
}

__global__ void k_rowptr_perm(const int* __restrict__ cnt, const int* __restrict__ psum,
                              int N, int E, int* __restrict__ rowptr, float* __restrict__ dis,
                              int* __restrict__ bcnt, int* __restrict__ perm){
  __shared__ int sh[256];
  __shared__ int lh[64];
  int tid = threadIdx.x; int n = blockIdx.x*256 + tid;
  int v = (n < N) ? cnt[n] : 0;
  sh[tid] = v;
  if (tid < 64) lh[tid] = 0;
  __syncthreads();
  int b = min(v, 63), r = 0;
  if (n < N) r = atomicAdd(&lh[b], 1);
  for (int off = 1; off < 256; off <<= 1){
    int t = (tid >= off) ? sh[tid - off] : 0;
    __syncthreads();
    sh[tid] += t;
    __syncthreads();
  }
  if (n < N){
    rowptr[n] = psum[blockIdx.x] + sh[tid] - v;
    dis[n] = 1.0f / sqrtf((float)(v + 1));
  }
  if (n == N-1) rowptr[N] = E;
  if (tid < 64){
    int c = lh[tid];
    lh[tid] = (c > 0) ? atomicAdd(&bcnt[tid], c) : 0;
  }
  __syncthreads();
  if (n < N) perm[lh[b] + r] = n;
}

__global__ void k_fill(const int* __restrict__ src, const int* __restrict__ dst, int E,
                       const int* __restrict__ rowptr, int* __restrict__ cnt,
                       const float* __restrict__ dis,
                       int* __restrict__ csr_src, float* __restrict__ csr_w){
  int e = blockIdx.x*256 + threadIdx.x; if (e >= E) return;
  int d = dst[e], s = src[e];
  int pos = atomicAdd(&cnt[d], 1);
  int slot = rowptr[d] + pos;
  csr_src[slot] = s;
  csr_w[slot] = dis[s]*dis[d];
}

// ---------------- h0 = x@proj_w + b, plus layer-0 quantization ----------------
// Round 8: writes h0 and hq QUARTER-MAJOR: buf[q*N*24 + n*24 + (c%24)], q = c/24.
__global__ __launch_bounds__(256) void k_h0(
  const float* __restrict__ x, const float* __restrict__ W, const float* __restrict__ bias,
  float* __restrict__ h0q, float* __restrict__ hq, unsigned kq0, unsigned kq1, int N)
{
  __shared__ float xs[64*65];
  __shared__ float wsh[64*96];
  int tid = threadIdx.x; int n0 = blockIdx.x*64;
  int cg = tid & 15, ng = tid >> 4; int c0 = cg*6;
  const size_t NQ = (size_t)N*24;
  float acc[4][6];
#pragma unroll
  for (int i=0;i<4;i++) for (int j=0;j<6;j++) acc[i][j]=0.f;
  for (int kc=0; kc<2; kc++){
    if (kc) __syncthreads();
    for (int q=tid; q<1536; q+=256)
      ((float4*)wsh)[q] = ((const float4*)(W + kc*64*96))[q];
    for (int q=tid; q<1024; q+=256){
      int g=q*4; int r=g>>6, col=g&63;
      int n=n0+r; int ns = n<N ? n : N-1;
      float4 v = ((const float4*)(x + (size_t)ns*128 + kc*64))[col>>2];
      xs[r*65+col]=v.x; xs[r*65+col+1]=v.y; xs[r*65+col+2]=v.z; xs[r*65+col+3]=v.w;
    }
    __syncthreads();
    for (int k=0;k<64;k++){
      float wv[6];
#pragma unroll
      for (int j=0;j<6;j++) wv[j]=wsh[k*96 + c0 + j];
#pragma unroll
      for (int i=0;i<4;i++){
        float xv = xs[(ng*4+i)*65 + k];
#pragma unroll
        for (int j=0;j<6;j++) acc[i][j] = fmaf(xv, wv[j], acc[i][j]);
      }
    }
  }
#pragma unroll
  for (int i=0;i<4;i++){
    int n = n0 + ng*4 + i; if (n >= N) continue;
#pragma unroll
    for (int j=0;j<6;j++){
      int c = c0 + j; int p = n*96 + c;
      int qq = c/24, qo = c%24;
      size_t addr = (size_t)qq*NQ + (size_t)n*24 + qo;
      float v = acc[i][j] + bias[c];
      h0q[addr] = v;
      unsigned bq = tf_bits(kq0, kq1, (unsigned)p);
      float b = u01_from_bits(bq) - 0.5f;     // delta = 1
      hq[addr] = floorf(v + b) - b;
    }
  }
}

// ---------------- quarter-partitioned gather ----------------
// grid = 8 * ceil(TILES/2); quarter q=(bid%8)>>1 -> XCD pair via %8 round-robin.
// Each block: 64 rows (perm order), 8 row-groups of 32 lanes; lane = slot(4)*6 + chpart(6);
// 4 edges in flight per step; shfl slot-reduction; writes t row-major (96B per row-quarter).
__global__ __launch_bounds__(256) void k_gather(
  const float* __restrict__ hq, const float* __restrict__ h0q, const float* __restrict__ dis,
  const int* __restrict__ rowptr, const int* __restrict__ csr_src, const float* __restrict__ csr_w,
  const int* __restrict__ perm, float* __restrict__ t, int N, int TILES)
{
  int bid = blockIdx.x;
  int q = (bid & 7) >> 1;
  int tile = (bid >> 3)*2 + (bid & 1);
  if (tile >= TILES) return;
  int lane = threadIdx.x & 31, ty = threadIdx.x >> 5;
  int slot = lane / 6;            // 0..3 active (lanes 0..23), 4..5 idle
  int c    = lane - slot*6;       // 0..5
  bool act = lane < 24;
  const float4* hq4 = (const float4*)hq + (size_t)q*((size_t)N*6);
  const float4* h04 = (const float4*)h0q + (size_t)q*((size_t)N*6);

  for (int pass = 0; pass < 8; pass++){
    int row = tile*64 + pass*8 + ty;
    if (row >= N) continue;                 // uniform per 32-lane group
    int n = perm[row];
    float d = dis[n]; float dd = d*d;
    int lo = rowptr[n], hi = rowptr[n+1];
    float4 acc = make_float4(0.f, 0.f, 0.f, 0.f);
    if (act && slot == 0){
      float4 self = hq4[(size_t)n*6 + c];
      acc.x = self.x*dd; acc.y = self.y*dd; acc.z = self.z*dd; acc.w = self.w*dd;
    }
    if (act){
      for (int s = lo; s < hi; s += 16){
        int   sn[4]; float w[4];
#pragma unroll
        for (int j = 0; j < 4; j++){
          int e = s + j*4 + slot;
          bool hv = e < hi;
          sn[j] = hv ? csr_src[e] : 0;
          w[j]  = hv ? csr_w[e]   : 0.f;
        }
        float4 g0 = hq4[(size_t)sn[0]*6 + c];
        float4 g1 = hq4[(size_t)sn[1]*6 + c];
        float4 g2 = hq4[(size_t)sn[2]*6 + c];
        float4 g3 = hq4[(size_t)sn[3]*6 + c];
        acc.x = fmaf(g0.x, w[0], acc.x); acc.y = fmaf(g0.y, w[0], acc.y);
        acc.z = fmaf(g0.z, w[0], acc.z); acc.w = fmaf(g0.w, w[0], acc.w);
        acc.x = fmaf(g1.x, w[1], acc.x); acc.y = fmaf(g1.y, w[1], acc.y);
        acc.z = fmaf(g1.z, w[1], acc.z); acc.w = fmaf(g1.w, w[1], acc.w);
        acc.x = fmaf(g2.x, w[2], acc.x); acc.y = fmaf(g2.y, w[2], acc.y);
        acc.z = fmaf(g2.z, w[2], acc.z); acc.w = fmaf(g2.w, w[2], acc.w);
        acc.x = fmaf(g3.x, w[3], acc.x); acc.y = fmaf(g3.y, w[3], acc.y);
        acc.z = fmaf(g3.z, w[3], acc.z); acc.w = fmaf(g3.w, w[3], acc.w);
      }
    }
    // reduce slots 0..3 -> slot 0 (lane layout slot*6+c: +12 then +6)
    acc.x += __shfl_down(acc.x, 12, 32); acc.y += __shfl_down(acc.y, 12, 32);
    acc.z += __shfl_down(acc.z, 12, 32); acc.w += __shfl_down(acc.w, 12, 32);
    acc.x += __shfl_down(acc.x,  6, 32); acc.y += __shfl_down(acc.y,  6, 32);
    acc.z += __shfl_down(acc.z,  6, 32); acc.w += __shfl_down(acc.w,  6, 32);
    if (lane < 6){
      float4 hz = h04[(size_t)n*6 + lane];
      float4 o;
      o.x = 0.9f*acc.x + 0.1f*hz.x;
      o.y = 0.9f*acc.y + 0.1f*hz.y;
      o.z = 0.9f*acc.z + 0.1f*hz.z;
      o.w = 0.9f*acc.w + 0.1f*hz.w;
      ((float4*)(t + (size_t)n*96 + q*24))[lane] = o;
    }
  }
}

// ---------------- M = t@W; h = (1-b)t + b*M; epilogue; write hq (quarter-major) ----------------
// 64-row tiles, W in four 24-row chunks, LDS 34816 B -> 4 blocks/CU.
__global__ __launch_bounds__(256, 4) void k_mmpost(
  const float* __restrict__ tbuf, const float* __restrict__ W,
  float betaf, float ombf,
  unsigned ke0, unsigned ke1, unsigned kd0, unsigned kd1,
  unsigned kq0, unsigned kq1, float delta_n, float invdelta_n,
  int do_dropout, int write_h,
  float* __restrict__ hq_out, float* __restrict__ h_out, int N)
{
  __shared__ float ts[64*100];   // 25600 B
  __shared__ float wsh[24*96];   // 9216 B
  int tid = threadIdx.x; int n0 = blockIdx.x*64;
  const size_t NQ = (size_t)N*24;

  for (int q = tid; q < 1536; q += 256){
    int r = q / 24, c4 = (q % 24) * 4;
    int n = n0 + r; int ns = n < N ? n : N - 1;
    float4 v = ((const float4*)(tbuf + (size_t)ns*96))[c4 >> 2];
    *((float4*)&ts[r*100 + c4]) = v;
  }

  int cg = tid & 7, ng = tid >> 3;   // cg 0..7, ng 0..31
  int c0 = cg * 12;
  int r0 = ng * 2;
  float acc[2][12];
#pragma unroll
  for (int i = 0; i < 2; i++)
#pragma unroll
    for (int j = 0; j < 12; j++) acc[i][j] = 0.f;

  for (int chunk = 0; chunk < 4; chunk++){
    __syncthreads();
    for (int q = tid; q < 576; q += 256)
      ((float4*)wsh)[q] = ((const float4*)(W + chunk*24*96))[q];
    __syncthreads();
#pragma unroll 4
    for (int kk = 0; kk < 24; kk++){
      int k = chunk*24 + kk;
      float4 w0 = *((const float4*)&wsh[kk*96 + c0]);
      float4 w1 = *((const float4*)&wsh[kk*96 + c0 + 4]);
      float4 w2 = *((const float4*)&wsh[kk*96 + c0 + 8]);
      float xv0 = ts[r0*100 + k];
      float xv1 = ts[(r0+1)*100 + k];
      acc[0][0] = fmaf(xv0, w0.x, acc[0][0]);  acc[0][1] = fmaf(xv0, w0.y, acc[0][1]);
      acc[0][2] = fmaf(xv0, w0.z, acc[0][2]);  acc[0][3] = fmaf(xv0, w0.w, acc[0][3]);
      acc[0][4] = fmaf(xv0, w1.x, acc[0][4]);  acc[0][5] = fmaf(xv0, w1.y, acc[0][5]);
      acc[0][6] = fmaf(xv0, w1.z, acc[0][6]);  acc[0][7] = fmaf(xv0, w1.w, acc[0][7]);
      acc[0][8] = fmaf(xv0, w2.x, acc[0][8]);  acc[0][9] = fmaf(xv0, w2.y, acc[0][9]);
      acc[0][10]= fmaf(xv0, w2.z, acc[0][10]); acc[0][11]= fmaf(xv0, w2.w, acc[0][11]);
      acc[1][0] = fmaf(xv1, w0.x, acc[1][0]);  acc[1][1] = fmaf(xv1, w0.y, acc[1][1]);
      acc[1][2] = fmaf(xv1, w0.z, acc[1][2]);  acc[1][3] = fmaf(xv1, w0.w, acc[1][3]);
      acc[1][4] = fmaf(xv1, w1.x, acc[1][4]);  acc[1][5] = fmaf(xv1, w1.y, acc[1][5]);
      acc[1][6] = fmaf(xv1, w1.z, acc[1][6]);  acc[1][7] = fmaf(xv1, w1.w, acc[1][7]);
      acc[1][8] = fmaf(xv1, w2.x, acc[1][8]);  acc[1][9] = fmaf(xv1, w2.y, acc[1][9]);
      acc[1][10]= fmaf(xv1, w2.z, acc[1][10]); acc[1][11]= fmaf(xv1, w2.w, acc[1][11]);
    }
  }

  const float LO = __uint_as_float(0xBF7FFFFFu);   // nextafter(-1,0)
  int qq = c0/24, qo = c0%24;                      // 12-col group lies in one quarter
#pragma unroll
  for (int i = 0; i < 2; i++){
    int n = n0 + r0 + i; if (n >= N) continue;
    float res[12];
#pragma unroll
    for (int j = 0; j < 12; j++){
      int c = c0 + j; int p = n*96 + c;
      float tv = ts[(r0+i)*100 + c];
      float hv = ombf*tv + betaf*acc[i][j];
      unsigned be = tf_bits(ke0, ke1, (unsigned)p);
      float uv = fmaxf(LO, u01_from_bits(be)*2.0f + LO);
      hv += 0.01f * (1.41421356f * erfinv_xla(uv));
      hv = fmaxf(hv, 0.0f);
      if (do_dropout){
        unsigned bd = tf_bits(kd0, kd1, (unsigned)p);
        hv = (bd < 0x80000000u) ? hv*2.0f : 0.0f;
      }
      if (!write_h){
        unsigned bq = tf_bits(kq0, kq1, (unsigned)p);
        float b = (u01_from_bits(bq) - 0.5f)*delta_n;
        hv = floorf((hv + b)*invdelta_n)*delta_n - b;
      }
      res[j] = hv;
    }
    float* dst = write_h ? (h_out + (size_t)n*96 + c0)
                         : (hq_out + (size_t)qq*NQ + (size_t)n*24 + qo);
#pragma unroll
    for (int j4 = 0; j4 < 3; j4++)
      *((float4*)&dst[j4*4]) = make_float4(res[j4*4], res[j4*4+1], res[j4*4+2], res[j4*4+3]);
  }
}

// ---------------- out = [h0, h] @ out_w + out_b (h0 read quarter-major) ----------------
__global__ __launch_bounds__(256) void k_final(
  const float* __restrict__ h0q, const float* __restrict__ h,
  const float* __restrict__ W, const float* __restrict__ bias,
  float* __restrict__ out, int N)
{
  __shared__ float xs[64*97];
  __shared__ float wsh[96*40];
  int tid = threadIdx.x; int n0 = blockIdx.x*64;
  int cg = tid & 7, ng = tid >> 3; int c0 = cg*5;
  const size_t NQ = (size_t)N*24;
  float acc[2][5];
#pragma unroll
  for (int i=0;i<2;i++) for (int j=0;j<5;j++) acc[i][j]=0.f;
  for (int ph=0; ph<2; ph++){
    if (ph) __syncthreads();
    for (int q=tid; q<960; q+=256)
      ((float4*)wsh)[q] = ((const float4*)(W + ph*96*40))[q];
    for (int q=tid; q<1536; q+=256){
      int g=q*4; int r=g/96, col=g%96;
      int n=n0+r; int ns = n<N ? n : N-1;
      float4 v;
      if (ph){
        v = ((const float4*)(h + (size_t)ns*96))[col>>2];
      } else {
        int qq = col/24, qo = col%24;
        v = *((const float4*)(h0q + (size_t)qq*NQ + (size_t)ns*24 + qo));
      }
      xs[r*97+col]=v.x; xs[r*97+col+1]=v.y; xs[r*97+col+2]=v.z; xs[r*97+col+3]=v.w;
    }
    __syncthreads();
    for (int k=0;k<96;k++){
      float wv[5];
#pragma unroll
      for (int j=0;j<5;j++) wv[j]=wsh[k*40 + c0 + j];
#pragma unroll
      for (int i=0;i<2;i++){
        float xv = xs[(ng*2+i)*97 + k];
#pragma unroll
        for (int j=0;j<5;j++) acc[i][j] = fmaf(xv, wv[j], acc[i][j]);
      }
    }
  }
#pragma unroll
  for (int i=0;i<2;i++){
    int n = n0 + ng*2 + i; if (n >= N) continue;
#pragma unroll
    for (int j=0;j<5;j++)
      out[(size_t)n*40 + c0 + j] = acc[i][j] + bias[c0 + j];
  }
}

// ---------------- host ----------------
static void tf_host(uint32_t k0, uint32_t k1, uint32_t x0, uint32_t x1,
                    uint32_t &y0, uint32_t &y1){
  uint32_t ks2 = k0 ^ k1 ^ 0x1BD11BDAu;
  x0 += k0; x1 += k1;
  auto R = [&](int r){ x0 += x1; x1 = (x1<<r)|(x1>>(32-r)); x1 ^= x0; };
  R(13);R(15);R(26);R(6);   x0 += k1;  x1 += ks2 + 1u;
  R(17);R(29);R(16);R(24);  x0 += ks2; x1 += k0 + 2u;
  R(13);R(15);R(26);R(6);   x0 += k0;  x1 += k1 + 3u;
  R(17);R(29);R(16);R(24);  x0 += k1;  x1 += ks2 + 4u;
  R(13);R(15);R(26);R(6);   x0 += ks2; x1 += k0 + 5u;
  y0 = x0; y1 = x1;
}

extern "C" void kernel_launch(void* const* d_in, const int* in_sizes, int n_in,
                              void* d_out, int out_size, void* d_ws, size_t ws_size,
                              hipStream_t stream)
{
  const float*    x       = (const float*)d_in[0];
  const unsigned* eraw    = (const unsigned*)d_in[1];
  const float*    proj_w  = (const float*)d_in[2];
  const float*    proj_b  = (const float*)d_in[3];
  const float*    conv_w  = (const float*)d_in[4];
  const float*    out_w   = (const float*)d_in[5];
  const float*    out_b   = (const float*)d_in[6];
  float* out = (float*)d_out;

  const int N = in_sizes[0] / INC;     // 50000
  const int E = in_sizes[1] / 2;       // 800000
  const size_t NH = (size_t)N * HID;

  float* ws     = (float*)d_ws;
  float* h0q    = ws;            // quarter-major
  float* hq     = h0q + NH;      // quarter-major, updated in place each layer
  float* tb     = hq + NH;       // t, row-major
  float* hb     = tb + NH;       // last-layer h, row-major
  float* dis    = hb + NH;
  int*   cnt    = (int*)(dis + N);
  int*   rowptr = cnt + N;
  int*   csr_src= rowptr + (N + 1);
  float* csr_w  = (float*)(csr_src + E);
  int*   srcb   = (int*)(csr_w + E);
  int*   dstb   = srcb + E;
  int*   flag   = dstb + E;
  int*   perm   = flag + 1;
  int*   bcnt   = perm + N;
  int*   psum   = bcnt + 64;
  (void)ws_size; (void)n_in; (void)out_size;

  // JAX key chain: key(42) -> per layer split(key,4) (partitionable foldlike)
  uint32_t kq[8][2], ke[8][2], kd[8][2];
  {
    uint32_t K0 = 0u, K1 = 42u;
    for (int k = 0; k < 8; k++){
      uint32_t y0, y1;
      tf_host(K0, K1, 0u, 0u, y0, y1); kq[k][0]=y0; kq[k][1]=y1;
      tf_host(K0, K1, 0u, 1u, y0, y1); ke[k][0]=y0; ke[k][1]=y1;
      tf_host(K0, K1, 0u, 2u, y0, y1); kd[k][0]=y0; kd[k][1]=y1;
      tf_host(K0, K1, 0u, 3u, y0, y1); K0=y0; K1=y1;
    }
  }

  const int gE    = (E + 255)/256;
  const int gN    = (N + 255)/256;
  const int gMM   = (N + 63)/64;       // 64-row tiles (h0, mmpost, final)
  const int TILES = gMM;
  const int gG    = 8 * ((TILES + 1)/2);

  hipMemsetAsync(cnt, 0, (size_t)N*4, stream);
  hipMemsetAsync(bcnt, 0, 64*4, stream);
  k_detect <<<1, 64, 0, stream>>>(eraw, flag);
  k_convcount<<<gE, 256, 0, stream>>>(eraw, flag, E, srcb, dstb, cnt);
  k_psum_histo<<<gN, 256, 0, stream>>>(cnt, N, psum, bcnt);
  k_scan2  <<<1, 256, 0, stream>>>(psum, gN, bcnt);
  k_rowptr_perm<<<gN, 256, 0, stream>>>(cnt, psum, N, E, rowptr, dis, bcnt, perm);
  hipMemsetAsync(cnt, 0, (size_t)N*4, stream);
  k_fill   <<<gE, 256, 0, stream>>>(srcb, dstb, E, rowptr, cnt, dis, csr_src, csr_w);

  k_h0<<<gMM, 256, 0, stream>>>(x, proj_w, proj_b, h0q, hq, kq[0][0], kq[0][1], N);

  for (int k = 0; k < 8; k++){
    double bd = log(0.5/(double)(k+1) + 1.0);
    float betaf = (float)bd;
    float ombf  = (float)(1.0 - bd);
    int last = (k == 7);
    float dn  = 1.0f/(float)(1 << (k+1));
    float idn = (float)(1 << (k+1));
    k_gather<<<gG, 256, 0, stream>>>(hq, h0q, dis, rowptr, csr_src, csr_w, perm, tb, N, TILES);
    k_mmpost<<<gMM, 256, 0, stream>>>(tb, conv_w + (size_t)k*HID*HID, betaf, ombf,
      ke[k][0], ke[k][1], kd[k][0], kd[k][1],
      last?0u:kq[k+1][0], last?0u:kq[k+1][1], dn, idn,
      !last, last, hq, hb, N);
  }

  k_final<<<gMM, 256, 0, stream>>>(h0q, hb, out_w, out_b, out, N);
}

// Round 9
// 1001.411 us; speedup vs baseline: 1.3891x; 1.3891x over previous
//
#include <hip/hip_runtime.h>
#include <hip/hip_fp16.h>
#include <cstdint>
#include <cmath>

#define HID 96
#define INC 128
#define OUTC 40

// ---------------- threefry2x32 (JAX exact) ----------------
__device__ __forceinline__ unsigned rotl32d(unsigned x, int r){ return (x<<r)|(x>>(32-r)); }

__device__ __forceinline__ void tf2x32_dev(unsigned k0, unsigned k1, unsigned x0, unsigned x1,
                                           unsigned &y0, unsigned &y1){
  unsigned ks2 = k0 ^ k1 ^ 0x1BD11BDAu;
  x0 += k0; x1 += k1;
#define TFR(r) { x0 += x1; x1 = rotl32d(x1, r); x1 ^= x0; }
  TFR(13) TFR(15) TFR(26) TFR(6)   x0 += k1;  x1 += ks2 + 1u;
  TFR(17) TFR(29) TFR(16) TFR(24)  x0 += ks2; x1 += k0 + 2u;
  TFR(13) TFR(15) TFR(26) TFR(6)   x0 += k0;  x1 += k1 + 3u;
  TFR(17) TFR(29) TFR(16) TFR(24)  x0 += k1;  x1 += ks2 + 4u;
  TFR(13) TFR(15) TFR(26) TFR(6)   x0 += ks2; x1 += k0 + 5u;
#undef TFR
  y0 = x0; y1 = x1;
}

__device__ __forceinline__ unsigned tf_bits(unsigned k0, unsigned k1, unsigned idx){
  unsigned y0, y1; tf2x32_dev(k0, k1, 0u, idx, y0, y1); return y0 ^ y1;
}

__device__ __forceinline__ float u01_from_bits(unsigned bits){
  return __uint_as_float((bits >> 9) | 0x3f800000u) - 1.0f;
}

// XLA f32 ErfInv polynomial
__device__ __forceinline__ float erfinv_xla(float x){
  float w = -log1pf(-x*x);
  float p;
  if (w < 5.0f){
    w = w - 2.5f;
    p = 2.81022636e-08f;
    p = fmaf(p,w, 3.43273939e-07f);
    p = fmaf(p,w,-3.5233877e-06f);
    p = fmaf(p,w,-4.39150654e-06f);
    p = fmaf(p,w, 0.00021858087f);
    p = fmaf(p,w,-0.00125372503f);
    p = fmaf(p,w,-0.00417768164f);
    p = fmaf(p,w, 0.246640727f);
    p = fmaf(p,w, 1.50140941f);
  } else {
    w = sqrtf(w) - 3.0f;
    p = -0.000200214257f;
    p = fmaf(p,w, 0.000100950558f);
    p = fmaf(p,w, 0.00134934322f);
    p = fmaf(p,w,-0.00367342844f);
    p = fmaf(p,w, 0.00573950773f);
    p = fmaf(p,w,-0.0076224613f);
    p = fmaf(p,w, 0.00943887047f);
    p = fmaf(p,w, 1.00167406f);
    p = fmaf(p,w, 2.83297682f);
  }
  return p*x;
}

// ---------------- setup kernels ----------------
__global__ void k_detect(const unsigned* __restrict__ raw, int* flag){
  unsigned v = raw[2*threadIdx.x + 1];
  unsigned long long m = __ballot(v == 0u);
  if (threadIdx.x == 0) *flag = (m == 0xFFFFFFFFFFFFFFFFull) ? 1 : 0;
}

__global__ void k_convcount(const unsigned* __restrict__ raw, const int* __restrict__ flag,
                            int E, int* __restrict__ src, int* __restrict__ dst,
                            int* __restrict__ cnt){
  int e = blockIdx.x*256 + threadIdx.x; if (e >= E) return;
  int s, d;
  if (*flag){ s = (int)raw[2*(size_t)e]; d = (int)raw[2*((size_t)E + e)]; }
  else      { const int* r = (const int*)raw; s = r[e]; d = r[E + e]; }
  src[e] = s; dst[e] = d;
  atomicAdd(&cnt[d], 1);
}

__global__ void k_psum_histo(const int* __restrict__ cnt, int N,
                             int* __restrict__ psum, int* __restrict__ bcnt){
  __shared__ int sh[256];
  __shared__ int lh[64];
  int tid = threadIdx.x; int n = blockIdx.x*256 + tid;
  int v = (n < N) ? cnt[n] : 0;
  sh[tid] = v;
  if (tid < 64) lh[tid] = 0;
  __syncthreads();
  if (n < N) atomicAdd(&lh[min(v, 63)], 1);
  for (int off = 128; off > 0; off >>= 1){
    __syncthreads();
    if (tid < off) sh[tid] += sh[tid + off];
  }
  __syncthreads();
  if (tid == 0) psum[blockIdx.x] = sh[0];
  if (tid < 64){
    int c = lh[tid];
    if (c > 0) atomicAdd(&bcnt[tid], c);
  }
}

__global__ void k_scan2(int* __restrict__ psum, int nb, int* __restrict__ bcnt){
  __shared__ int sh[256];
  __shared__ int sb[64];
  int tid = threadIdx.x;
  int v = (tid < nb) ? psum[tid] : 0;
  sh[tid] = v;
  if (tid < 64) sb[tid] = bcnt[tid];
  __syncthreads();
  for (int off = 1; off < 256; off <<= 1){
    int t = (tid >= off) ? sh[tid - off] : 0;
    __syncthreads();
    sh[tid] += t;
    __syncthreads();
  }
  if (tid < nb) psum[tid] = sh[tid] - v;   // exclusive
  if (tid < 64){                           // descending: high degree first
    int off = 0;
    for (int b2 = tid+1; b2 < 64; b2++) off += sb[b2];
    bcnt[tid] = off;
  }
}

__global__ void k_rowptr_perm(const int* __restrict__ cnt, const int* __restrict__ psum,
                              int N, int E, int* __restrict__ rowptr, float* __restrict__ dis,
                              int* __restrict__ bcnt, int* __restrict__ perm){
  __shared__ int sh[256];
  __shared__ int lh[64];
  int tid = threadIdx.x; int n = blockIdx.x*256 + tid;
  int v = (n < N) ? cnt[n] : 0;
  sh[tid] = v;
  if (tid < 64) lh[tid] = 0;
  __syncthreads();
  int b = min(v, 63), r = 0;
  if (n < N) r = atomicAdd(&lh[b], 1);
  for (int off = 1; off < 256; off <<= 1){
    int t = (tid >= off) ? sh[tid - off] : 0;
    __syncthreads();
    sh[tid] += t;
    __syncthreads();
  }
  if (n < N){
    rowptr[n] = psum[blockIdx.x] + sh[tid] - v;
    dis[n] = 1.0f / sqrtf((float)(v + 1));
  }
  if (n == N-1) rowptr[N] = E;
  if (tid < 64){
    int c = lh[tid];
    lh[tid] = (c > 0) ? atomicAdd(&bcnt[tid], c) : 0;
  }
  __syncthreads();
  if (n < N) perm[lh[b] + r] = n;
}

__global__ void k_fill(const int* __restrict__ src, const int* __restrict__ dst, int E,
                       const int* __restrict__ rowptr, int* __restrict__ cnt,
                       const float* __restrict__ dis,
                       int* __restrict__ csr_src, float* __restrict__ csr_w){
  int e = blockIdx.x*256 + threadIdx.x; if (e >= E) return;
  int d = dst[e], s = src[e];
  int pos = atomicAdd(&cnt[d], 1);
  int slot = rowptr[d] + pos;
  csr_src[slot] = s;
  csr_w[slot] = dis[s]*dis[d];
}

// ---------------- h0 = x@proj_w + b, plus layer-0 quantization (delta=1) ----------------
// Round 9: hq stored fp16 (RNE). h0 stays fp32 row-major.
__global__ __launch_bounds__(256) void k_h0(
  const float* __restrict__ x, const float* __restrict__ W, const float* __restrict__ bias,
  float* __restrict__ h0, __half* __restrict__ hq, unsigned kq0, unsigned kq1, int N)
{
  __shared__ float xs[64*65];
  __shared__ float wsh[64*96];
  int tid = threadIdx.x; int n0 = blockIdx.x*64;
  int cg = tid & 15, ng = tid >> 4; int c0 = cg*6;
  float acc[4][6];
#pragma unroll
  for (int i=0;i<4;i++) for (int j=0;j<6;j++) acc[i][j]=0.f;
  for (int kc=0; kc<2; kc++){
    if (kc) __syncthreads();
    for (int q=tid; q<1536; q+=256)
      ((float4*)wsh)[q] = ((const float4*)(W + kc*64*96))[q];
    for (int q=tid; q<1024; q+=256){
      int g=q*4; int r=g>>6, col=g&63;
      int n=n0+r; int ns = n<N ? n : N-1;
      float4 v = ((const float4*)(x + (size_t)ns*128 + kc*64))[col>>2];
      xs[r*65+col]=v.x; xs[r*65+col+1]=v.y; xs[r*65+col+2]=v.z; xs[r*65+col+3]=v.w;
    }
    __syncthreads();
    for (int k=0;k<64;k++){
      float wv[6];
#pragma unroll
      for (int j=0;j<6;j++) wv[j]=wsh[k*96 + c0 + j];
#pragma unroll
      for (int i=0;i<4;i++){
        float xv = xs[(ng*4+i)*65 + k];
#pragma unroll
        for (int j=0;j<6;j++) acc[i][j] = fmaf(xv, wv[j], acc[i][j]);
      }
    }
  }
#pragma unroll
  for (int i=0;i<4;i++){
    int n = n0 + ng*4 + i; if (n >= N) continue;
#pragma unroll
    for (int j=0;j<6;j++){
      int c = c0 + j; int p = n*96 + c;
      float v = acc[i][j] + bias[c];
      h0[p] = v;
      unsigned bq = tf_bits(kq0, kq1, (unsigned)p);
      float b = u01_from_bits(bq) - 0.5f;     // delta = 1
      hq[(size_t)n*96 + c] = __float2half_rn(floorf(v + b) - b);
    }
  }
}

// ---------------- fused per-layer kernel (r6 structure + fp16 gather table) ----------------
// 64-row tiles; LDS = ts 25600 + wsh 9216 + rowmap 256 = 35072 B -> 4 blocks/CU.
// Gather reads hq as uint2 (4 fp16/lane, 24 lanes = 96 ch = 192 B/row).
__global__ __launch_bounds__(256, 4) void k_layer(
  const __half* __restrict__ hq_in, const float* __restrict__ h0, const float* __restrict__ dis,
  const int* __restrict__ rowptr, const int* __restrict__ csr_src, const float* __restrict__ csr_w,
  const int* __restrict__ perm, const float* __restrict__ W,
  float betaf, float ombf,
  unsigned ke0, unsigned ke1, unsigned kd0, unsigned kd1,
  unsigned kq0, unsigned kq1, float delta_n, float invdelta_n,
  int do_dropout, int write_h,
  __half* __restrict__ hq_out, float* __restrict__ h_out, int N)
{
  __shared__ float ts[64*100];   // 25600 B t tile, stride 100
  __shared__ float wsh[24*96];   // 9216 B W K-chunk
  __shared__ int rowmap[64];
  int tid = threadIdx.x;
  int tx = tid & 31, ty = tid >> 5;    // 8 rows in flight
  int n0 = blockIdx.x*64;

  const uint2* hq2 = (const uint2*)hq_in;    // 24 uint2 per row (4 fp16 each)
  const float4* h04 = (const float4*)h0;

  // ---- phase 1: gather 64 rows, 8 passes of 8 concurrent rows ----
#pragma unroll 1
  for (int pass = 0; pass < 8; pass++){
    int r = pass*8 + ty;
    int row = n0 + r;
    int n = (row < N) ? perm[row] : -1;
    if (tx == 0) rowmap[r] = n;
    if (tx < 24){
      float4 o = make_float4(0.f, 0.f, 0.f, 0.f);
      if (n >= 0){
        float d = dis[n];
        int lo = rowptr[n], hi = rowptr[n+1];
        uint2 sraw = hq2[(size_t)n*24 + tx];
        float2 s01 = __half22float2(*(__half2*)&sraw.x);
        float2 s23 = __half22float2(*(__half2*)&sraw.y);
        float dd = d*d;
        float ax = s01.x*dd, ay = s01.y*dd, az = s23.x*dd, aw = s23.y*dd;
        for (int s = lo; s < hi; s += 8){
          int   sn[8];
          float w[8];
#pragma unroll
          for (int j = 0; j < 8; j++){
            bool hv = (s + j) < hi;
            sn[j] = hv ? csr_src[s + j] : csr_src[s];
            w[j]  = hv ? csr_w[s + j]   : 0.0f;
          }
          uint2 g[8];
#pragma unroll
          for (int j = 0; j < 8; j++) g[j] = hq2[(size_t)sn[j]*24 + tx];
#pragma unroll
          for (int j = 0; j < 8; j++){
            float2 f01 = __half22float2(*(__half2*)&g[j].x);
            float2 f23 = __half22float2(*(__half2*)&g[j].y);
            ax = fmaf(f01.x, w[j], ax); ay = fmaf(f01.y, w[j], ay);
            az = fmaf(f23.x, w[j], az); aw = fmaf(f23.y, w[j], aw);
          }
        }
        float4 hz = h04[(size_t)n*24 + tx];
        o.x = 0.9f*ax + 0.1f*hz.x;
        o.y = 0.9f*ay + 0.1f*hz.y;
        o.z = 0.9f*az + 0.1f*hz.z;
        o.w = 0.9f*aw + 0.1f*hz.w;
      }
      *((float4*)&ts[r*100 + tx*4]) = o;
    }
  }

  // ---- phase 2: matmul + epilogue ----
  int cg = tid & 7, ng = tid >> 3;   // cg 0..7, ng 0..31
  int c0 = cg * 12;
  int r0 = ng * 2;
  float acc[2][12];
#pragma unroll
  for (int i = 0; i < 2; i++)
#pragma unroll
    for (int j = 0; j < 12; j++) acc[i][j] = 0.f;

  for (int chunk = 0; chunk < 4; chunk++){
    __syncthreads();
    for (int q = tid; q < 576; q += 256)
      ((float4*)wsh)[q] = ((const float4*)(W + chunk*24*96))[q];
    __syncthreads();
#pragma unroll 4
    for (int kk = 0; kk < 24; kk++){
      int k = chunk*24 + kk;
      float4 w0 = *((const float4*)&wsh[kk*96 + c0]);
      float4 w1 = *((const float4*)&wsh[kk*96 + c0 + 4]);
      float4 w2 = *((const float4*)&wsh[kk*96 + c0 + 8]);
      float xv0 = ts[r0*100 + k];
      float xv1 = ts[(r0+1)*100 + k];
      acc[0][0] = fmaf(xv0, w0.x, acc[0][0]);  acc[0][1] = fmaf(xv0, w0.y, acc[0][1]);
      acc[0][2] = fmaf(xv0, w0.z, acc[0][2]);  acc[0][3] = fmaf(xv0, w0.w, acc[0][3]);
      acc[0][4] = fmaf(xv0, w1.x, acc[0][4]);  acc[0][5] = fmaf(xv0, w1.y, acc[0][5]);
      acc[0][6] = fmaf(xv0, w1.z, acc[0][6]);  acc[0][7] = fmaf(xv0, w1.w, acc[0][7]);
      acc[0][8] = fmaf(xv0, w2.x, acc[0][8]);  acc[0][9] = fmaf(xv0, w2.y, acc[0][9]);
      acc[0][10]= fmaf(xv0, w2.z, acc[0][10]); acc[0][11]= fmaf(xv0, w2.w, acc[0][11]);
      acc[1][0] = fmaf(xv1, w0.x, acc[1][0]);  acc[1][1] = fmaf(xv1, w0.y, acc[1][1]);
      acc[1][2] = fmaf(xv1, w0.z, acc[1][2]);  acc[1][3] = fmaf(xv1, w0.w, acc[1][3]);
      acc[1][4] = fmaf(xv1, w1.x, acc[1][4]);  acc[1][5] = fmaf(xv1, w1.y, acc[1][5]);
      acc[1][6] = fmaf(xv1, w1.z, acc[1][6]);  acc[1][7] = fmaf(xv1, w1.w, acc[1][7]);
      acc[1][8] = fmaf(xv1, w2.x, acc[1][8]);  acc[1][9] = fmaf(xv1, w2.y, acc[1][9]);
      acc[1][10]= fmaf(xv1, w2.z, acc[1][10]); acc[1][11]= fmaf(xv1, w2.w, acc[1][11]);
    }
  }

  const float LO = __uint_as_float(0xBF7FFFFFu);   // nextafter(-1,0)
#pragma unroll
  for (int i = 0; i < 2; i++){
    int n = rowmap[r0 + i]; if (n < 0) continue;
    float res[12];
#pragma unroll
    for (int j = 0; j < 12; j++){
      int c = c0 + j; int p = n*96 + c;
      float tv = ts[(r0+i)*100 + c];
      float hv = ombf*tv + betaf*acc[i][j];
      unsigned be = tf_bits(ke0, ke1, (unsigned)p);
      float uv = fmaxf(LO, u01_from_bits(be)*2.0f + LO);
      hv += 0.01f * (1.41421356f * erfinv_xla(uv));
      hv = fmaxf(hv, 0.0f);
      if (do_dropout){
        unsigned bd = tf_bits(kd0, kd1, (unsigned)p);
        hv = (bd < 0x80000000u) ? hv*2.0f : 0.0f;
      }
      if (!write_h){
        unsigned bq = tf_bits(kq0, kq1, (unsigned)p);
        float b = (u01_from_bits(bq) - 0.5f)*delta_n;
        hv = floorf((hv + b)*invdelta_n)*delta_n - b;
      }
      res[j] = hv;
    }
    if (write_h){
      float* dst = h_out + (size_t)n*96 + c0;
#pragma unroll
      for (int j4 = 0; j4 < 3; j4++)
        *((float4*)&dst[j4*4]) = make_float4(res[j4*4], res[j4*4+1], res[j4*4+2], res[j4*4+3]);
    } else {
      // 12 fp16 = 3x uint2, 8-B aligned (c0*2 = 24*cg bytes)
      uint2* dst = (uint2*)(hq_out + (size_t)n*96 + c0);
#pragma unroll
      for (int j4 = 0; j4 < 3; j4++){
        unsigned lo2 = (unsigned)__half_as_ushort(__float2half_rn(res[j4*4+0]))
                     | ((unsigned)__half_as_ushort(__float2half_rn(res[j4*4+1])) << 16);
        unsigned hi2 = (unsigned)__half_as_ushort(__float2half_rn(res[j4*4+2]))
                     | ((unsigned)__half_as_ushort(__float2half_rn(res[j4*4+3])) << 16);
        dst[j4] = make_uint2(lo2, hi2);
      }
    }
  }
}

// ---------------- out = [h0, h] @ out_w + out_b ----------------
__global__ __launch_bounds__(256) void k_final(
  const float* __restrict__ h0, const float* __restrict__ h,
  const float* __restrict__ W, const float* __restrict__ bias,
  float* __restrict__ out, int N)
{
  __shared__ float xs[64*97];
  __shared__ float wsh[96*40];
  int tid = threadIdx.x; int n0 = blockIdx.x*64;
  int cg = tid & 7, ng = tid >> 3; int c0 = cg*5;
  float acc[2][5];
#pragma unroll
  for (int i=0;i<2;i++) for (int j=0;j<5;j++) acc[i][j]=0.f;
  for (int ph=0; ph<2; ph++){
    if (ph) __syncthreads();
    const float* xsrc = ph ? h : h0;
    for (int q=tid; q<960; q+=256)
      ((float4*)wsh)[q] = ((const float4*)(W + ph*96*40))[q];
    for (int q=tid; q<1536; q+=256){
      int g=q*4; int r=g/96, col=g%96;
      int n=n0+r; int ns = n<N ? n : N-1;
      float4 v = ((const float4*)(xsrc + (size_t)ns*96))[col>>2];
      xs[r*97+col]=v.x; xs[r*97+col+1]=v.y; xs[r*97+col+2]=v.z; xs[r*97+col+3]=v.w;
    }
    __syncthreads();
    for (int k=0;k<96;k++){
      float wv[5];
#pragma unroll
      for (int j=0;j<5;j++) wv[j]=wsh[k*40 + c0 + j];
#pragma unroll
      for (int i=0;i<2;i++){
        float xv = xs[(ng*2+i)*97 + k];
#pragma unroll
        for (int j=0;j<5;j++) acc[i][j] = fmaf(xv, wv[j], acc[i][j]);
      }
    }
  }
#pragma unroll
  for (int i=0;i<2;i++){
    int n = n0 + ng*2 + i; if (n >= N) continue;
#pragma unroll
    for (int j=0;j<5;j++)
      out[(size_t)n*40 + c0 + j] = acc[i][j] + bias[c0 + j];
  }
}

// ---------------- host ----------------
static void tf_host(uint32_t k0, uint32_t k1, uint32_t x0, uint32_t x1,
                    uint32_t &y0, uint32_t &y1){
  uint32_t ks2 = k0 ^ k1 ^ 0x1BD11BDAu;
  x0 += k0; x1 += k1;
  auto R = [&](int r){ x0 += x1; x1 = (x1<<r)|(x1>>(32-r)); x1 ^= x0; };
  R(13);R(15);R(26);R(6);   x0 += k1;  x1 += ks2 + 1u;
  R(17);R(29);R(16);R(24);  x0 += ks2; x1 += k0 + 2u;
  R(13);R(15);R(26);R(6);   x0 += k0;  x1 += k1 + 3u;
  R(17);R(29);R(16);R(24);  x0 += k1;  x1 += ks2 + 4u;
  R(13);R(15);R(26);R(6);   x0 += ks2; x1 += k0 + 5u;
  y0 = x0; y1 = x1;
}

extern "C" void kernel_launch(void* const* d_in, const int* in_sizes, int n_in,
                              void* d_out, int out_size, void* d_ws, size_t ws_size,
                              hipStream_t stream)
{
  const float*    x       = (const float*)d_in[0];
  const unsigned* eraw    = (const unsigned*)d_in[1];
  const float*    proj_w  = (const float*)d_in[2];
  const float*    proj_b  = (const float*)d_in[3];
  const float*    conv_w  = (const float*)d_in[4];
  const float*    out_w   = (const float*)d_in[5];
  const float*    out_b   = (const float*)d_in[6];
  float* out = (float*)d_out;

  const int N = in_sizes[0] / INC;     // 50000
  const int E = in_sizes[1] / 2;       // 800000
  const size_t NH = (size_t)N * HID;

  float*  ws     = (float*)d_ws;
  float*  h0     = ws;                       // NH f32
  __half* hqA    = (__half*)(h0 + NH);       // NH fp16 (ping)
  __half* hqB    = hqA + NH;                 // NH fp16 (pong)
  float*  hb     = (float*)(hqB + NH);       // NH f32, last-layer h
  float*  dis    = hb + NH;
  int*    cnt    = (int*)(dis + N);
  int*    rowptr = cnt + N;
  int*    csr_src= rowptr + (N + 1);
  float*  csr_w  = (float*)(csr_src + E);
  int*    srcb   = (int*)(csr_w + E);
  int*    dstb   = srcb + E;
  int*    flag   = dstb + E;
  int*    perm   = flag + 1;
  int*    bcnt   = perm + N;
  int*    psum   = bcnt + 64;
  (void)ws_size; (void)n_in; (void)out_size;

  // JAX key chain: key(42) -> per layer split(key,4) (partitionable foldlike)
  uint32_t kq[8][2], ke[8][2], kd[8][2];
  {
    uint32_t K0 = 0u, K1 = 42u;
    for (int k = 0; k < 8; k++){
      uint32_t y0, y1;
      tf_host(K0, K1, 0u, 0u, y0, y1); kq[k][0]=y0; kq[k][1]=y1;
      tf_host(K0, K1, 0u, 1u, y0, y1); ke[k][0]=y0; ke[k][1]=y1;
      tf_host(K0, K1, 0u, 2u, y0, y1); kd[k][0]=y0; kd[k][1]=y1;
      tf_host(K0, K1, 0u, 3u, y0, y1); K0=y0; K1=y1;
    }
  }

  const int gE  = (E + 255)/256;
  const int gN  = (N + 255)/256;
  const int gMM = (N + 63)/64;

  hipMemsetAsync(cnt, 0, (size_t)N*4, stream);
  hipMemsetAsync(bcnt, 0, 64*4, stream);
  k_detect <<<1, 64, 0, stream>>>(eraw, flag);
  k_convcount<<<gE, 256, 0, stream>>>(eraw, flag, E, srcb, dstb, cnt);
  k_psum_histo<<<gN, 256, 0, stream>>>(cnt, N, psum, bcnt);
  k_scan2  <<<1, 256, 0, stream>>>(psum, gN, bcnt);
  k_rowptr_perm<<<gN, 256, 0, stream>>>(cnt, psum, N, E, rowptr, dis, bcnt, perm);
  hipMemsetAsync(cnt, 0, (size_t)N*4, stream);
  k_fill   <<<gE, 256, 0, stream>>>(srcb, dstb, E, rowptr, cnt, dis, csr_src, csr_w);

  k_h0<<<gMM, 256, 0, stream>>>(x, proj_w, proj_b, h0, hqA, kq[0][0], kq[0][1], N);

  for (int k = 0; k < 8; k++){
    double bd = log(0.5/(double)(k+1) + 1.0);
    float betaf = (float)bd;
    float ombf  = (float)(1.0 - bd);
    int last = (k == 7);
    float dn  = 1.0f/(float)(1 << (k+1));
    float idn = (float)(1 << (k+1));
    const __half* hin  = (k & 1) ? hqB : hqA;   // ping-pong: no read/write race
    __half*       hout = (k & 1) ? hqA : hqB;
    k_layer<<<gMM, 256, 0, stream>>>(hin, h0, dis, rowptr, csr_src, csr_w, perm,
      conv_w + (size_t)k*HID*HID, betaf, ombf,
      ke[k][0], ke[k][1], kd[k][0], kd[k][1],
      last?0u:kq[k+1][0], last?0u:kq[k+1][1], dn, idn,
      !last, last, hout, hb, N);
  }

  k_final<<<gMM, 256, 0, stream>>>(h0, hb, out_w, out_b, out, N);
}